// Round 16
// baseline (178.643 us; speedup 1.0000x reference)
//
#include <hip/hip_runtime.h>
#include <hip/hip_bf16.h>
#include <math.h>

// HMM forward (logZ), K=64 tags, V=50000, D=128, BATCH=8192, L=126.
// r21: MEASUREMENT round — idempotent repeat diagnostic. Theory scorecard
// for the scan's apparent ~60us: chain latency (r18: 126->63 steps = only
// -5us), XCD replication (r19: null), L2 pre-warm (r20: null). The
// r17<->r18 differential bounds the step-dependent part at ~76ns/step
// (~5us total) -> ~57us of my scan attribution is a FIXED cost with no
// structural explanation. All attribution so far is subtraction against
// the 44.5us harness fill rows and may be wrong. This round: launch the
// PURE k_scan3 three times (reads btn8/A/sumexp -> rewrites identical
// out; bitwise idempotent).
//   T_scan = (dur_r21 - 125.2)/2 exactly, assumption-free.
//   If T_scan >~ 44: three k_scan3 top-5 rows w/ direct counters
//   (VALUBusy/MfmaUtil/FETCH/Occupancy) + measured scan->scan launch gap.
//   Branches: ~60 -> mystery is in-kernel, counters localize; ~15-25 ->
//   subtraction was wrong, wall lives in gaps/fill; <5 -> scan is free.
// Kernels byte-identical r18 (best measured, 125.2us).
//
// fp8 row layout: tag k = 32*h + 8*qA + j  ->  byte 16*qA + 8*h + j.
//
// ws layout (r12):
//   [0, 3,200,000)        btn8[v][64]   fp8e4m3  raw exp(logit), permuted order
//   [3,200,000, +16384)   A[i][j]       f32      softmax(WA, col BOS=-inf)+EPS
//   [3,216,384, +256)     sumexp[k]     f32
//   [3,216,640, +200704)  partial[k][784] f32    per-block column sums

#define KT 64
#define VV 50000
#define DD 128
#define BOS_T 62
#define EOS_T 63
#define LLEN 126
#define EPSF 1e-45f
#define SCALE_F 65536.0f
#define LOG_TOTAL_SCALE (2016.0f * 0.6931471805599453f)
#define NBLK 782          // k_emit grid
#define PBLK 784          // padded partial row
#define PFD 9             // prefetch depth
#define HSTEPS 63         // steps per direction (126/2)
#define HROUNDS (HSTEPS / PFD)   // 7

#define BTN_OFF   0
#define A_OFF     3200000
#define SUM_OFF   3216384
#define PART_OFF  3216640

typedef short short8 __attribute__((ext_vector_type(8)));
typedef float f32x4  __attribute__((ext_vector_type(4)));
typedef float f32x2  __attribute__((ext_vector_type(2)));

union U8 { short8 v; unsigned u[4]; short s[8]; };

static __device__ inline unsigned short f2bf_u(float x) {
    __hip_bfloat16 h = __float2bfloat16(x);
    return *reinterpret_cast<unsigned short*>(&h);
}
static __device__ inline short f2bf(float x) { return (short)f2bf_u(x); }
static __device__ inline float bf2f(short s) {
    union { unsigned u; float f; } c;
    c.u = ((unsigned)(unsigned short)s) << 16;
    return c.f;
}

#if __has_builtin(__builtin_amdgcn_cvt_pk_bf16_f32)
typedef __bf16 bf16x2 __attribute__((ext_vector_type(2)));
static __device__ inline unsigned pk2(float a, float b) {
    bf16x2 r = __builtin_amdgcn_cvt_pk_bf16_f32(a, b);
    return *reinterpret_cast<unsigned*>(&r);
}
#else
static __device__ inline unsigned pk2(float a, float b) {
    union { float f; unsigned u; } ua, ub;
    ua.f = a; ub.f = b;
    return ((ua.u + 0x8000u) >> 16) | ((ub.u + 0x8000u) & 0xFFFF0000u);
}
#endif

// ---- fp8 e4m3fn pack/unpack (values here are positive normals in [0.7,1.5])
#if __has_builtin(__builtin_amdgcn_cvt_pk_fp8_f32)
static __device__ inline unsigned pk4f8(float a, float b, float c, float d) {
    int v = __builtin_amdgcn_cvt_pk_fp8_f32(a, b, 0, false);
    v = __builtin_amdgcn_cvt_pk_fp8_f32(c, d, v, true);
    return (unsigned)v;
}
#else
static __device__ inline unsigned enc1f8(float x) {
    union { float f; unsigned u; } c; c.f = x;
    unsigned u = c.u & 0x7FFFFFFFu;
    unsigned r = u + 0x7FFFFu + ((u >> 20) & 1u);   // RNE to 3 mantissa bits
    return ((r >> 20) - (120u << 3)) & 0x7Fu;       // rebias 127->7
}
static __device__ inline unsigned pk4f8(float a, float b, float c, float d) {
    return enc1f8(a) | (enc1f8(b) << 8) | (enc1f8(c) << 16) | (enc1f8(d) << 24);
}
#endif

#if __has_builtin(__builtin_amdgcn_cvt_pk_f32_fp8)
static __device__ inline f32x2 dec2lo(unsigned w) { return __builtin_amdgcn_cvt_pk_f32_fp8((int)w, false); }
static __device__ inline f32x2 dec2hi(unsigned w) { return __builtin_amdgcn_cvt_pk_f32_fp8((int)w, true); }
#else
static __device__ inline float dec1f8(unsigned b) {
    union { unsigned u; float f; } c;
    c.u = ((b & 0x80u) << 24) | (((b & 0x7Fu) << 20) + (120u << 23));
    return c.f;
}
static __device__ inline f32x2 dec2lo(unsigned w) { f32x2 r; r.x = dec1f8(w & 0xFF); r.y = dec1f8((w >> 8) & 0xFF); return r; }
static __device__ inline f32x2 dec2hi(unsigned w) { f32x2 r; r.x = dec1f8((w >> 16) & 0xFF); r.y = dec1f8(w >> 24); return r; }
#endif

// ---------------------------------------------------------------- btn8[v][pos(k)] = fp8(exp(ThetaB[k].E[v]))  (MFMA GEMM)
__global__ __launch_bounds__(256) void k_emit(const float* __restrict__ ThetaB,
                                              const float* __restrict__ E,
                                              unsigned char* __restrict__ btn8,
                                              float* __restrict__ partial) {
    __shared__ float red[4][KT];
    int t    = threadIdx.x;
    int lane = t & 63;
    int w    = t >> 6;
    int n    = lane & 15;
    int q    = lane >> 4;
    int v0   = (blockIdx.x * 4 + w) * 16;

    int rowE = v0 + n;
    bool valid = rowE < VV;
    rowE = valid ? rowE : VV - 1;
    float4 ex[4][2];
#pragma unroll
    for (int kt = 0; kt < 4; ++kt) {
        const float* p = E + (size_t)rowE * DD + kt * 32 + q * 8;
        ex[kt][0] = *(const float4*)p;
        ex[kt][1] = *(const float4*)(p + 4);
    }

    short8 Th[4][4];
#pragma unroll
    for (int kt = 0; kt < 4; ++kt)
#pragma unroll
        for (int mt = 0; mt < 4; ++mt) {
            const float* p = ThetaB + (mt * 16 + n) * DD + kt * 32 + q * 8;
            float4 x = *(const float4*)p;
            float4 y = *(const float4*)(p + 4);
            U8 f;
            f.u[0] = pk2(x.x, x.y); f.u[1] = pk2(x.z, x.w);
            f.u[2] = pk2(y.x, y.y); f.u[3] = pk2(y.z, y.w);
            Th[kt][mt] = f.v;
        }

    short8 Ef[4];
#pragma unroll
    for (int kt = 0; kt < 4; ++kt) {
        U8 f;
        f.u[0] = pk2(ex[kt][0].x, ex[kt][0].y); f.u[1] = pk2(ex[kt][0].z, ex[kt][0].w);
        f.u[2] = pk2(ex[kt][1].x, ex[kt][1].y); f.u[3] = pk2(ex[kt][1].z, ex[kt][1].w);
        Ef[kt] = f.v;
    }

#pragma unroll
    for (int mt = 0; mt < 4; ++mt) {
        f32x4 C = {0.f, 0.f, 0.f, 0.f};
#pragma unroll
        for (int kt = 0; kt < 4; ++kt)
            C = __builtin_amdgcn_mfma_f32_16x16x32_bf16(Th[kt][mt], Ef[kt], C, 0, 0, 0);
        float e[4];
#pragma unroll
        for (int r = 0; r < 4; ++r) e[r] = __expf(C[r]);
        if (valid) {
            // tag tt = mt*16 + q*4 + r -> byte 16*qA + 8*h + j
            int pos = 16 * ((2 * mt + (q >> 1)) & 3) + 8 * (mt >> 1) + (q & 1) * 4;
            *(unsigned*)(btn8 + (size_t)rowE * KT + pos) = pk4f8(e[0], e[1], e[2], e[3]);
        }
#pragma unroll
        for (int r = 0; r < 4; ++r) {
            float s = valid ? e[r] : 0.0f;
            s += __shfl_xor(s, 1, 64);
            s += __shfl_xor(s, 2, 64);
            s += __shfl_xor(s, 4, 64);
            s += __shfl_xor(s, 8, 64);
            if (n == 0) red[w][mt * 16 + q * 4 + r] = s;
        }
    }
    __syncthreads();
    if (w == 0) {
        float s = red[0][lane] + red[1][lane] + red[2][lane] + red[3][lane];
        partial[lane * PBLK + blockIdx.x] = s;
    }
}

// ---------------------------------------------------------------- sumexp[k] = sum partial[k][:]; A row k = softmax(WA row k)
__global__ __launch_bounds__(256) void k_sumA(const float* __restrict__ partial,
                                              const float* __restrict__ WA,
                                              float* __restrict__ sumexp,
                                              float* __restrict__ A) {
    __shared__ float r[4];
    int k = blockIdx.x;
    int t = threadIdx.x;
    float s = 0.0f;
    for (int i = t; i < NBLK; i += 256) s += partial[k * PBLK + i];
#pragma unroll
    for (int off = 32; off > 0; off >>= 1) s += __shfl_xor(s, off, 64);
    if ((t & 63) == 0) r[t >> 6] = s;
    __syncthreads();
    if (t == 0) sumexp[k] = r[0] + r[1] + r[2] + r[3];
    if (t < 64) {
        float wv = WA[k * KT + t];
        float e = (t == BOS_T) ? 0.0f : __expf(wv);
        float se = e;
#pragma unroll
        for (int off = 32; off > 0; off >>= 1) se += __shfl_xor(se, off, 64);
        A[k * KT + t] = e / se + EPSF;
    }
}

// ---------------------------------------------------------------- split scan
// 512 blocks x 128 threads (2 waves), 16 sentences per block.
// wave0: alpha_63 forward (words 0..62). wave1: beta_63 backward
// (words 125..63), y <- A''(e .* y) from A[:,EOS].
// Combine: logZ = log(sum x*y) - LOG_TOTAL_SCALE.  (Pure/idempotent.)
__global__ __launch_bounds__(128) void k_scan3(const int* __restrict__ words,
                                               const unsigned char* __restrict__ btn8,
                                               const float* __restrict__ A,
                                               const float* __restrict__ sumexp,
                                               float* __restrict__ out) {
    __shared__ int shw[16 * LLEN];    // 8064 B
    __shared__ float scl[KT];         // 256 B
    __shared__ float ldx[KT][16];     // 4096 B  alpha_63 (tag, sentence)
    __shared__ float ldy[KT][16];     // 4096 B  beta_63
    int t    = threadIdx.x;
    int lane = t & 63;
    int w    = t >> 6;                // 0 = forward, 1 = backward
    int n    = lane & 15;
    int qA   = lane >> 4;
    int b0   = blockIdx.x * 16;

    // stage word indices (both waves cooperate)
    {
        const uint4* src = (const uint4*)(words + (size_t)b0 * LLEN);
        uint4* dst = (uint4*)shw;
        for (int idx = t; idx < (16 * LLEN) / 4; idx += 128)
            dst[idx] = src[idx];
    }
    // contracted-tag scale table for the backward A-operand
    if (t < KT)
        scl[t] = (t == BOS_T || t == EOS_T) ? 0.0f : (SCALE_F / sumexp[t]);
    __syncthreads();

    const int wrow = n * LLEN;

    if (w == 0) {
        // ================= forward: words 0..62 from one-hot BOS =================
        short8 Af[2][4];
#pragma unroll
        for (int mt = 0; mt < 4; ++mt) {
            int tagn = 32 * (mt >> 1) + 8 * (n >> 2) + 4 * (mt & 1) + (n & 3);
            float s = sumexp[tagn];
            float rsn = (tagn == BOS_T || tagn == EOS_T) ? 0.0f : (SCALE_F / s);
#pragma unroll
            for (int kt = 0; kt < 2; ++kt) {
                U8 f;
#pragma unroll
                for (int j = 0; j < 8; ++j)
                    f.s[j] = f2bf(A[(kt * 32 + qA * 8 + j) * KT + tagn] * rsn);
                Af[kt][mt] = f.v;
            }
        }
        short8 B0, B1;
        {
            U8 z; z.u[0] = z.u[1] = z.u[2] = z.u[3] = 0;
            B0 = z.v;
            U8 o; o.u[0] = o.u[1] = o.u[2] = o.u[3] = 0;
            if (qA == 3) o.s[6] = (short)0x3F80;   // bf16(1.0) at tag 62 = BOS
            B1 = o.v;
        }

        uint4 pf[PFD];
        int   wdn[PFD];
#pragma unroll
        for (int j = 0; j < PFD; ++j) {
            int wd = shw[wrow + j];
            pf[j] = *(const uint4*)(btn8 + (size_t)wd * KT + qA * 16);
        }
#pragma unroll
        for (int j = 0; j < PFD; ++j)
            wdn[j] = shw[wrow + PFD + j];

        for (int r = 0; r < HROUNDS; ++r) {
#pragma unroll
            for (int j = 0; j < PFD; ++j) {
                uint4 rc = pf[j];
                pf[j] = *(const uint4*)(btn8 + (size_t)wdn[j] * KT + qA * 16);
                int s18 = r * PFD + j + 2 * PFD;
                s18 = s18 < HSTEPS ? s18 : HSTEPS - 1;
                wdn[j] = shw[wrow + s18];

                f32x2 d0 = dec2lo(rc.x), d1 = dec2hi(rc.x);
                f32x2 d2 = dec2lo(rc.y), d3 = dec2hi(rc.y);
                f32x2 d4 = dec2lo(rc.z), d5 = dec2hi(rc.z);
                f32x2 d6 = dec2lo(rc.w), d7 = dec2hi(rc.w);

                f32x4 C[4];
#pragma unroll
                for (int mt = 0; mt < 4; ++mt) {
                    f32x4 acc = {0.f, 0.f, 0.f, 0.f};
                    acc = __builtin_amdgcn_mfma_f32_16x16x32_bf16(Af[0][mt], B0, acc, 0, 0, 0);
                    acc = __builtin_amdgcn_mfma_f32_16x16x32_bf16(Af[1][mt], B1, acc, 0, 0, 0);
                    C[mt] = acc;
                }
                U8 f0, f1;
                f0.u[0] = pk2(C[0][0] * d0.x, C[0][1] * d0.y);
                f0.u[1] = pk2(C[0][2] * d1.x, C[0][3] * d1.y);
                f0.u[2] = pk2(C[1][0] * d2.x, C[1][1] * d2.y);
                f0.u[3] = pk2(C[1][2] * d3.x, C[1][3] * d3.y);
                f1.u[0] = pk2(C[2][0] * d4.x, C[2][1] * d4.y);
                f1.u[1] = pk2(C[2][2] * d5.x, C[2][3] * d5.y);
                f1.u[2] = pk2(C[3][0] * d6.x, C[3][1] * d6.y);
                f1.u[3] = pk2(C[3][2] * d7.x, C[3][3] * d7.y);
                B0 = f0.v; B1 = f1.v;
            }
        }
        // x63 -> LDS: B-slot tag = kt*32 + qA*8 + j
        U8 bx0, bx1; bx0.v = B0; bx1.v = B1;
#pragma unroll
        for (int j = 0; j < 8; ++j) {
            ldx[qA * 8 + j][n]      = bf2f(bx0.s[j]);
            ldx[32 + qA * 8 + j][n] = bf2f(bx1.s[j]);
        }
    } else {
        // ================= backward: words 125..63 from y_T = A[:,EOS] ==========
        short8 Af[2][4];
#pragma unroll
        for (int mt = 0; mt < 4; ++mt) {
            int tagn = 32 * (mt >> 1) + 8 * (n >> 2) + 4 * (mt & 1) + (n & 3);
#pragma unroll
            for (int kt = 0; kt < 2; ++kt) {
                U8 f;
#pragma unroll
                for (int j = 0; j < 8; ++j) {
                    int kc = kt * 32 + qA * 8 + j;
                    f.s[j] = f2bf(A[tagn * KT + kc] * scl[kc]);
                }
                Af[kt][mt] = f.v;
            }
        }
        // y_T in C-layout: C[mt][r] at (n, qA) = A[tag(mt,qA,r), EOS]
        f32x4 C[4];
#pragma unroll
        for (int mt = 0; mt < 4; ++mt)
#pragma unroll
            for (int r = 0; r < 4; ++r) {
                int tg = 32 * (mt >> 1) + 8 * qA + 4 * (mt & 1) + r;
                C[mt][r] = A[tg * KT + EOS_T];
            }

        uint4 pf[PFD];
        int   wdn[PFD];
#pragma unroll
        for (int j = 0; j < PFD; ++j) {
            int wd = shw[wrow + (LLEN - 1 - j)];
            pf[j] = *(const uint4*)(btn8 + (size_t)wd * KT + qA * 16);
        }
#pragma unroll
        for (int j = 0; j < PFD; ++j)
            wdn[j] = shw[wrow + (LLEN - 1 - (PFD + j))];

        for (int r = 0; r < HROUNDS; ++r) {
#pragma unroll
            for (int j = 0; j < PFD; ++j) {
                uint4 rc = pf[j];
                pf[j] = *(const uint4*)(btn8 + (size_t)wdn[j] * KT + qA * 16);
                int itn = r * PFD + j + 2 * PFD;
                itn = itn < HSTEPS ? itn : HSTEPS - 1;
                wdn[j] = shw[wrow + (LLEN - 1 - itn)];

                f32x2 d0 = dec2lo(rc.x), d1 = dec2hi(rc.x);
                f32x2 d2 = dec2lo(rc.y), d3 = dec2hi(rc.y);
                f32x2 d4 = dec2lo(rc.z), d5 = dec2hi(rc.z);
                f32x2 d6 = dec2lo(rc.w), d7 = dec2hi(rc.w);

                // B = pk2(C .* e)  (elementwise BEFORE matvec in bwd)
                U8 f0, f1;
                f0.u[0] = pk2(C[0][0] * d0.x, C[0][1] * d0.y);
                f0.u[1] = pk2(C[0][2] * d1.x, C[0][3] * d1.y);
                f0.u[2] = pk2(C[1][0] * d2.x, C[1][1] * d2.y);
                f0.u[3] = pk2(C[1][2] * d3.x, C[1][3] * d3.y);
                f1.u[0] = pk2(C[2][0] * d4.x, C[2][1] * d4.y);
                f1.u[1] = pk2(C[2][2] * d5.x, C[2][3] * d5.y);
                f1.u[2] = pk2(C[3][0] * d6.x, C[3][1] * d6.y);
                f1.u[3] = pk2(C[3][2] * d7.x, C[3][3] * d7.y);
                short8 B0 = f0.v, B1 = f1.v;

#pragma unroll
                for (int mt = 0; mt < 4; ++mt) {
                    f32x4 acc = {0.f, 0.f, 0.f, 0.f};
                    acc = __builtin_amdgcn_mfma_f32_16x16x32_bf16(Af[0][mt], B0, acc, 0, 0, 0);
                    acc = __builtin_amdgcn_mfma_f32_16x16x32_bf16(Af[1][mt], B1, acc, 0, 0, 0);
                    C[mt] = acc;
                }
            }
        }
        // y63 -> LDS: C-position tag = 32*(mt>>1) + 8*qA + 4*(mt&1) + r
#pragma unroll
        for (int mt = 0; mt < 4; ++mt)
#pragma unroll
            for (int r = 0; r < 4; ++r) {
                int tg = 32 * (mt >> 1) + 8 * qA + 4 * (mt & 1) + r;
                ldy[tg][n] = C[mt][r];
            }
    }
    __syncthreads();

    // combine: logZ[n] = log(sum_tag x*y) - LOG_TOTAL_SCALE  (wave 0)
    if (w == 0) {
        float s = 0.0f;
#pragma unroll
        for (int kk = 0; kk < 16; ++kk) {
            int tg = qA * 16 + kk;
            s += ldx[tg][n] * ldy[tg][n];
        }
        s += __shfl_xor(s, 16, 64);
        s += __shfl_xor(s, 32, 64);
        if (qA == 0)
            out[b0 + n] = logf(s) - LOG_TOTAL_SCALE;
    }
}

extern "C" void kernel_launch(void* const* d_in, const int* in_sizes, int n_in,
                              void* d_out, int out_size, void* d_ws, size_t ws_size,
                              hipStream_t stream) {
    const int*   words  = (const int*)d_in[0];     // [8192,126]
    const float* ThetaB = (const float*)d_in[1];   // [64,128]
    const float* WA     = (const float*)d_in[2];   // [64,64]
    const float* E      = (const float*)d_in[3];   // [50000,128]
    float* out = (float*)d_out;                    // [8192]

    char* ws = (char*)d_ws;
    unsigned char* btn8 = (unsigned char*)(ws + BTN_OFF);
    float* A       = (float*)(ws + A_OFF);
    float* sumexp  = (float*)(ws + SUM_OFF);
    float* partial = (float*)(ws + PART_OFF);

    k_emit<<<NBLK, 256, 0, stream>>>(ThetaB, E, btn8, partial);
    k_sumA<<<KT, 256, 0, stream>>>(partial, WA, sumexp, A);
    // DIAGNOSTIC: k_scan3 is pure/idempotent — launch 3x.
    // T_scan = (dur - dur_r18)/2; each instance surfaces in top-5 if >~44us.
    k_scan3<<<8192 / 16, 128, 0, stream>>>(words, btn8, A, sumexp, out);
    k_scan3<<<8192 / 16, 128, 0, stream>>>(words, btn8, A, sumexp, out);
    k_scan3<<<8192 / 16, 128, 0, stream>>>(words, btn8, A, sumexp, out);
}

// Round 17
// 170.146 us; speedup vs baseline: 1.0499x; 1.0499x over previous
//
#include <hip/hip_runtime.h>
#include <hip/hip_bf16.h>
#include <math.h>

// HMM forward (logZ), K=64 tags, V=50000, D=128, BATCH=8192, L=126.
// r22: MEASUREMENT round 2 — emit repeat diagnostic. r21's scan x3 gave
// T_scan+gap = (178.6-125.2)/2 = 26.7us -> the scan is ~23us, NOT ~60;
// r19/r20's gather theories chased an attribution artifact. Rebuilt ledger
// for r18's 125.2: fill 44.5 (measured, fixed) + scan ~23 (measured) +
// sumA ~4 + gaps ~9-14 (bounded by r21) + EMIT ~30-40 BY SUBTRACTION.
// First-principles emit model is ~8us (25.6MB E @ HBM) -> 4-5x gap, same
// smell as the scan fiction. Real suspect: btn8 stores are scattered 4B
// writes (r19's 8x replication of them cost +11us for 22MB). This round:
// k_emit is idempotent (rewrites same btn8/partial values) -> launch 3x.
//   T_emit+gap = (dur - 125.2)/2, assumption-free.
// Branches: dur ~185-195 -> emit 30-35 confirmed, next round fixes store
// coalescing (lane-shuffle to 64B row stores); dur ~145-155 -> emit 8-12,
// residual is harness/gaps -> reduce kernel count; dur ~135 -> gaps own it.
// Kernels byte-identical r18 (best, 125.2us).
//
// fp8 row layout: tag k = 32*h + 8*qA + j  ->  byte 16*qA + 8*h + j.
//
// ws layout (r12):
//   [0, 3,200,000)        btn8[v][64]   fp8e4m3  raw exp(logit), permuted order
//   [3,200,000, +16384)   A[i][j]       f32      softmax(WA, col BOS=-inf)+EPS
//   [3,216,384, +256)     sumexp[k]     f32
//   [3,216,640, +200704)  partial[k][784] f32    per-block column sums

#define KT 64
#define VV 50000
#define DD 128
#define BOS_T 62
#define EOS_T 63
#define LLEN 126
#define EPSF 1e-45f
#define SCALE_F 65536.0f
#define LOG_TOTAL_SCALE (2016.0f * 0.6931471805599453f)
#define NBLK 782          // k_emit grid
#define PBLK 784          // padded partial row
#define PFD 9             // prefetch depth
#define HSTEPS 63         // steps per direction (126/2)
#define HROUNDS (HSTEPS / PFD)   // 7

#define BTN_OFF   0
#define A_OFF     3200000
#define SUM_OFF   3216384
#define PART_OFF  3216640

typedef short short8 __attribute__((ext_vector_type(8)));
typedef float f32x4  __attribute__((ext_vector_type(4)));
typedef float f32x2  __attribute__((ext_vector_type(2)));

union U8 { short8 v; unsigned u[4]; short s[8]; };

static __device__ inline unsigned short f2bf_u(float x) {
    __hip_bfloat16 h = __float2bfloat16(x);
    return *reinterpret_cast<unsigned short*>(&h);
}
static __device__ inline short f2bf(float x) { return (short)f2bf_u(x); }
static __device__ inline float bf2f(short s) {
    union { unsigned u; float f; } c;
    c.u = ((unsigned)(unsigned short)s) << 16;
    return c.f;
}

#if __has_builtin(__builtin_amdgcn_cvt_pk_bf16_f32)
typedef __bf16 bf16x2 __attribute__((ext_vector_type(2)));
static __device__ inline unsigned pk2(float a, float b) {
    bf16x2 r = __builtin_amdgcn_cvt_pk_bf16_f32(a, b);
    return *reinterpret_cast<unsigned*>(&r);
}
#else
static __device__ inline unsigned pk2(float a, float b) {
    union { float f; unsigned u; } ua, ub;
    ua.f = a; ub.f = b;
    return ((ua.u + 0x8000u) >> 16) | ((ub.u + 0x8000u) & 0xFFFF0000u);
}
#endif

// ---- fp8 e4m3fn pack/unpack (values here are positive normals in [0.7,1.5])
#if __has_builtin(__builtin_amdgcn_cvt_pk_fp8_f32)
static __device__ inline unsigned pk4f8(float a, float b, float c, float d) {
    int v = __builtin_amdgcn_cvt_pk_fp8_f32(a, b, 0, false);
    v = __builtin_amdgcn_cvt_pk_fp8_f32(c, d, v, true);
    return (unsigned)v;
}
#else
static __device__ inline unsigned enc1f8(float x) {
    union { float f; unsigned u; } c; c.f = x;
    unsigned u = c.u & 0x7FFFFFFFu;
    unsigned r = u + 0x7FFFFu + ((u >> 20) & 1u);   // RNE to 3 mantissa bits
    return ((r >> 20) - (120u << 3)) & 0x7Fu;       // rebias 127->7
}
static __device__ inline unsigned pk4f8(float a, float b, float c, float d) {
    return enc1f8(a) | (enc1f8(b) << 8) | (enc1f8(c) << 16) | (enc1f8(d) << 24);
}
#endif

#if __has_builtin(__builtin_amdgcn_cvt_pk_f32_fp8)
static __device__ inline f32x2 dec2lo(unsigned w) { return __builtin_amdgcn_cvt_pk_f32_fp8((int)w, false); }
static __device__ inline f32x2 dec2hi(unsigned w) { return __builtin_amdgcn_cvt_pk_f32_fp8((int)w, true); }
#else
static __device__ inline float dec1f8(unsigned b) {
    union { unsigned u; float f; } c;
    c.u = ((b & 0x80u) << 24) | (((b & 0x7Fu) << 20) + (120u << 23));
    return c.f;
}
static __device__ inline f32x2 dec2lo(unsigned w) { f32x2 r; r.x = dec1f8(w & 0xFF); r.y = dec1f8((w >> 8) & 0xFF); return r; }
static __device__ inline f32x2 dec2hi(unsigned w) { f32x2 r; r.x = dec1f8((w >> 16) & 0xFF); r.y = dec1f8(w >> 24); return r; }
#endif

// ---------------------------------------------------------------- btn8[v][pos(k)] = fp8(exp(ThetaB[k].E[v]))  (MFMA GEMM)
__global__ __launch_bounds__(256) void k_emit(const float* __restrict__ ThetaB,
                                              const float* __restrict__ E,
                                              unsigned char* __restrict__ btn8,
                                              float* __restrict__ partial) {
    __shared__ float red[4][KT];
    int t    = threadIdx.x;
    int lane = t & 63;
    int w    = t >> 6;
    int n    = lane & 15;
    int q    = lane >> 4;
    int v0   = (blockIdx.x * 4 + w) * 16;

    int rowE = v0 + n;
    bool valid = rowE < VV;
    rowE = valid ? rowE : VV - 1;
    float4 ex[4][2];
#pragma unroll
    for (int kt = 0; kt < 4; ++kt) {
        const float* p = E + (size_t)rowE * DD + kt * 32 + q * 8;
        ex[kt][0] = *(const float4*)p;
        ex[kt][1] = *(const float4*)(p + 4);
    }

    short8 Th[4][4];
#pragma unroll
    for (int kt = 0; kt < 4; ++kt)
#pragma unroll
        for (int mt = 0; mt < 4; ++mt) {
            const float* p = ThetaB + (mt * 16 + n) * DD + kt * 32 + q * 8;
            float4 x = *(const float4*)p;
            float4 y = *(const float4*)(p + 4);
            U8 f;
            f.u[0] = pk2(x.x, x.y); f.u[1] = pk2(x.z, x.w);
            f.u[2] = pk2(y.x, y.y); f.u[3] = pk2(y.z, y.w);
            Th[kt][mt] = f.v;
        }

    short8 Ef[4];
#pragma unroll
    for (int kt = 0; kt < 4; ++kt) {
        U8 f;
        f.u[0] = pk2(ex[kt][0].x, ex[kt][0].y); f.u[1] = pk2(ex[kt][0].z, ex[kt][0].w);
        f.u[2] = pk2(ex[kt][1].x, ex[kt][1].y); f.u[3] = pk2(ex[kt][1].z, ex[kt][1].w);
        Ef[kt] = f.v;
    }

#pragma unroll
    for (int mt = 0; mt < 4; ++mt) {
        f32x4 C = {0.f, 0.f, 0.f, 0.f};
#pragma unroll
        for (int kt = 0; kt < 4; ++kt)
            C = __builtin_amdgcn_mfma_f32_16x16x32_bf16(Th[kt][mt], Ef[kt], C, 0, 0, 0);
        float e[4];
#pragma unroll
        for (int r = 0; r < 4; ++r) e[r] = __expf(C[r]);
        if (valid) {
            // tag tt = mt*16 + q*4 + r -> byte 16*qA + 8*h + j
            int pos = 16 * ((2 * mt + (q >> 1)) & 3) + 8 * (mt >> 1) + (q & 1) * 4;
            *(unsigned*)(btn8 + (size_t)rowE * KT + pos) = pk4f8(e[0], e[1], e[2], e[3]);
        }
#pragma unroll
        for (int r = 0; r < 4; ++r) {
            float s = valid ? e[r] : 0.0f;
            s += __shfl_xor(s, 1, 64);
            s += __shfl_xor(s, 2, 64);
            s += __shfl_xor(s, 4, 64);
            s += __shfl_xor(s, 8, 64);
            if (n == 0) red[w][mt * 16 + q * 4 + r] = s;
        }
    }
    __syncthreads();
    if (w == 0) {
        float s = red[0][lane] + red[1][lane] + red[2][lane] + red[3][lane];
        partial[lane * PBLK + blockIdx.x] = s;
    }
}

// ---------------------------------------------------------------- sumexp[k] = sum partial[k][:]; A row k = softmax(WA row k)
__global__ __launch_bounds__(256) void k_sumA(const float* __restrict__ partial,
                                              const float* __restrict__ WA,
                                              float* __restrict__ sumexp,
                                              float* __restrict__ A) {
    __shared__ float r[4];
    int k = blockIdx.x;
    int t = threadIdx.x;
    float s = 0.0f;
    for (int i = t; i < NBLK; i += 256) s += partial[k * PBLK + i];
#pragma unroll
    for (int off = 32; off > 0; off >>= 1) s += __shfl_xor(s, off, 64);
    if ((t & 63) == 0) r[t >> 6] = s;
    __syncthreads();
    if (t == 0) sumexp[k] = r[0] + r[1] + r[2] + r[3];
    if (t < 64) {
        float wv = WA[k * KT + t];
        float e = (t == BOS_T) ? 0.0f : __expf(wv);
        float se = e;
#pragma unroll
        for (int off = 32; off > 0; off >>= 1) se += __shfl_xor(se, off, 64);
        A[k * KT + t] = e / se + EPSF;
    }
}

// ---------------------------------------------------------------- split scan
// 512 blocks x 128 threads (2 waves), 16 sentences per block.
// wave0: alpha_63 forward (words 0..62). wave1: beta_63 backward
// (words 125..63), y <- A''(e .* y) from A[:,EOS].
// Combine: logZ = log(sum x*y) - LOG_TOTAL_SCALE.
__global__ __launch_bounds__(128) void k_scan3(const int* __restrict__ words,
                                               const unsigned char* __restrict__ btn8,
                                               const float* __restrict__ A,
                                               const float* __restrict__ sumexp,
                                               float* __restrict__ out) {
    __shared__ int shw[16 * LLEN];    // 8064 B
    __shared__ float scl[KT];         // 256 B
    __shared__ float ldx[KT][16];     // 4096 B  alpha_63 (tag, sentence)
    __shared__ float ldy[KT][16];     // 4096 B  beta_63
    int t    = threadIdx.x;
    int lane = t & 63;
    int w    = t >> 6;                // 0 = forward, 1 = backward
    int n    = lane & 15;
    int qA   = lane >> 4;
    int b0   = blockIdx.x * 16;

    // stage word indices (both waves cooperate)
    {
        const uint4* src = (const uint4*)(words + (size_t)b0 * LLEN);
        uint4* dst = (uint4*)shw;
        for (int idx = t; idx < (16 * LLEN) / 4; idx += 128)
            dst[idx] = src[idx];
    }
    // contracted-tag scale table for the backward A-operand
    if (t < KT)
        scl[t] = (t == BOS_T || t == EOS_T) ? 0.0f : (SCALE_F / sumexp[t]);
    __syncthreads();

    const int wrow = n * LLEN;

    if (w == 0) {
        // ================= forward: words 0..62 from one-hot BOS =================
        short8 Af[2][4];
#pragma unroll
        for (int mt = 0; mt < 4; ++mt) {
            int tagn = 32 * (mt >> 1) + 8 * (n >> 2) + 4 * (mt & 1) + (n & 3);
            float s = sumexp[tagn];
            float rsn = (tagn == BOS_T || tagn == EOS_T) ? 0.0f : (SCALE_F / s);
#pragma unroll
            for (int kt = 0; kt < 2; ++kt) {
                U8 f;
#pragma unroll
                for (int j = 0; j < 8; ++j)
                    f.s[j] = f2bf(A[(kt * 32 + qA * 8 + j) * KT + tagn] * rsn);
                Af[kt][mt] = f.v;
            }
        }
        short8 B0, B1;
        {
            U8 z; z.u[0] = z.u[1] = z.u[2] = z.u[3] = 0;
            B0 = z.v;
            U8 o; o.u[0] = o.u[1] = o.u[2] = o.u[3] = 0;
            if (qA == 3) o.s[6] = (short)0x3F80;   // bf16(1.0) at tag 62 = BOS
            B1 = o.v;
        }

        uint4 pf[PFD];
        int   wdn[PFD];
#pragma unroll
        for (int j = 0; j < PFD; ++j) {
            int wd = shw[wrow + j];
            pf[j] = *(const uint4*)(btn8 + (size_t)wd * KT + qA * 16);
        }
#pragma unroll
        for (int j = 0; j < PFD; ++j)
            wdn[j] = shw[wrow + PFD + j];

        for (int r = 0; r < HROUNDS; ++r) {
#pragma unroll
            for (int j = 0; j < PFD; ++j) {
                uint4 rc = pf[j];
                pf[j] = *(const uint4*)(btn8 + (size_t)wdn[j] * KT + qA * 16);
                int s18 = r * PFD + j + 2 * PFD;
                s18 = s18 < HSTEPS ? s18 : HSTEPS - 1;
                wdn[j] = shw[wrow + s18];

                f32x2 d0 = dec2lo(rc.x), d1 = dec2hi(rc.x);
                f32x2 d2 = dec2lo(rc.y), d3 = dec2hi(rc.y);
                f32x2 d4 = dec2lo(rc.z), d5 = dec2hi(rc.z);
                f32x2 d6 = dec2lo(rc.w), d7 = dec2hi(rc.w);

                f32x4 C[4];
#pragma unroll
                for (int mt = 0; mt < 4; ++mt) {
                    f32x4 acc = {0.f, 0.f, 0.f, 0.f};
                    acc = __builtin_amdgcn_mfma_f32_16x16x32_bf16(Af[0][mt], B0, acc, 0, 0, 0);
                    acc = __builtin_amdgcn_mfma_f32_16x16x32_bf16(Af[1][mt], B1, acc, 0, 0, 0);
                    C[mt] = acc;
                }
                U8 f0, f1;
                f0.u[0] = pk2(C[0][0] * d0.x, C[0][1] * d0.y);
                f0.u[1] = pk2(C[0][2] * d1.x, C[0][3] * d1.y);
                f0.u[2] = pk2(C[1][0] * d2.x, C[1][1] * d2.y);
                f0.u[3] = pk2(C[1][2] * d3.x, C[1][3] * d3.y);
                f1.u[0] = pk2(C[2][0] * d4.x, C[2][1] * d4.y);
                f1.u[1] = pk2(C[2][2] * d5.x, C[2][3] * d5.y);
                f1.u[2] = pk2(C[3][0] * d6.x, C[3][1] * d6.y);
                f1.u[3] = pk2(C[3][2] * d7.x, C[3][3] * d7.y);
                B0 = f0.v; B1 = f1.v;
            }
        }
        // x63 -> LDS: B-slot tag = kt*32 + qA*8 + j
        U8 bx0, bx1; bx0.v = B0; bx1.v = B1;
#pragma unroll
        for (int j = 0; j < 8; ++j) {
            ldx[qA * 8 + j][n]      = bf2f(bx0.s[j]);
            ldx[32 + qA * 8 + j][n] = bf2f(bx1.s[j]);
        }
    } else {
        // ================= backward: words 125..63 from y_T = A[:,EOS] ==========
        short8 Af[2][4];
#pragma unroll
        for (int mt = 0; mt < 4; ++mt) {
            int tagn = 32 * (mt >> 1) + 8 * (n >> 2) + 4 * (mt & 1) + (n & 3);
#pragma unroll
            for (int kt = 0; kt < 2; ++kt) {
                U8 f;
#pragma unroll
                for (int j = 0; j < 8; ++j) {
                    int kc = kt * 32 + qA * 8 + j;
                    f.s[j] = f2bf(A[tagn * KT + kc] * scl[kc]);
                }
                Af[kt][mt] = f.v;
            }
        }
        // y_T in C-layout: C[mt][r] at (n, qA) = A[tag(mt,qA,r), EOS]
        f32x4 C[4];
#pragma unroll
        for (int mt = 0; mt < 4; ++mt)
#pragma unroll
            for (int r = 0; r < 4; ++r) {
                int tg = 32 * (mt >> 1) + 8 * qA + 4 * (mt & 1) + r;
                C[mt][r] = A[tg * KT + EOS_T];
            }

        uint4 pf[PFD];
        int   wdn[PFD];
#pragma unroll
        for (int j = 0; j < PFD; ++j) {
            int wd = shw[wrow + (LLEN - 1 - j)];
            pf[j] = *(const uint4*)(btn8 + (size_t)wd * KT + qA * 16);
        }
#pragma unroll
        for (int j = 0; j < PFD; ++j)
            wdn[j] = shw[wrow + (LLEN - 1 - (PFD + j))];

        for (int r = 0; r < HROUNDS; ++r) {
#pragma unroll
            for (int j = 0; j < PFD; ++j) {
                uint4 rc = pf[j];
                pf[j] = *(const uint4*)(btn8 + (size_t)wdn[j] * KT + qA * 16);
                int itn = r * PFD + j + 2 * PFD;
                itn = itn < HSTEPS ? itn : HSTEPS - 1;
                wdn[j] = shw[wrow + (LLEN - 1 - itn)];

                f32x2 d0 = dec2lo(rc.x), d1 = dec2hi(rc.x);
                f32x2 d2 = dec2lo(rc.y), d3 = dec2hi(rc.y);
                f32x2 d4 = dec2lo(rc.z), d5 = dec2hi(rc.z);
                f32x2 d6 = dec2lo(rc.w), d7 = dec2hi(rc.w);

                // B = pk2(C .* e)  (elementwise BEFORE matvec in bwd)
                U8 f0, f1;
                f0.u[0] = pk2(C[0][0] * d0.x, C[0][1] * d0.y);
                f0.u[1] = pk2(C[0][2] * d1.x, C[0][3] * d1.y);
                f0.u[2] = pk2(C[1][0] * d2.x, C[1][1] * d2.y);
                f0.u[3] = pk2(C[1][2] * d3.x, C[1][3] * d3.y);
                f1.u[0] = pk2(C[2][0] * d4.x, C[2][1] * d4.y);
                f1.u[1] = pk2(C[2][2] * d5.x, C[2][3] * d5.y);
                f1.u[2] = pk2(C[3][0] * d6.x, C[3][1] * d6.y);
                f1.u[3] = pk2(C[3][2] * d7.x, C[3][3] * d7.y);
                short8 B0 = f0.v, B1 = f1.v;

#pragma unroll
                for (int mt = 0; mt < 4; ++mt) {
                    f32x4 acc = {0.f, 0.f, 0.f, 0.f};
                    acc = __builtin_amdgcn_mfma_f32_16x16x32_bf16(Af[0][mt], B0, acc, 0, 0, 0);
                    acc = __builtin_amdgcn_mfma_f32_16x16x32_bf16(Af[1][mt], B1, acc, 0, 0, 0);
                    C[mt] = acc;
                }
            }
        }
        // y63 -> LDS: C-position tag = 32*(mt>>1) + 8*qA + 4*(mt&1) + r
#pragma unroll
        for (int mt = 0; mt < 4; ++mt)
#pragma unroll
            for (int r = 0; r < 4; ++r) {
                int tg = 32 * (mt >> 1) + 8 * qA + 4 * (mt & 1) + r;
                ldy[tg][n] = C[mt][r];
            }
    }
    __syncthreads();

    // combine: logZ[n] = log(sum_tag x*y) - LOG_TOTAL_SCALE  (wave 0)
    if (w == 0) {
        float s = 0.0f;
#pragma unroll
        for (int kk = 0; kk < 16; ++kk) {
            int tg = qA * 16 + kk;
            s += ldx[tg][n] * ldy[tg][n];
        }
        s += __shfl_xor(s, 16, 64);
        s += __shfl_xor(s, 32, 64);
        if (qA == 0)
            out[b0 + n] = logf(s) - LOG_TOTAL_SCALE;
    }
}

extern "C" void kernel_launch(void* const* d_in, const int* in_sizes, int n_in,
                              void* d_out, int out_size, void* d_ws, size_t ws_size,
                              hipStream_t stream) {
    const int*   words  = (const int*)d_in[0];     // [8192,126]
    const float* ThetaB = (const float*)d_in[1];   // [64,128]
    const float* WA     = (const float*)d_in[2];   // [64,64]
    const float* E      = (const float*)d_in[3];   // [50000,128]
    float* out = (float*)d_out;                    // [8192]

    char* ws = (char*)d_ws;
    unsigned char* btn8 = (unsigned char*)(ws + BTN_OFF);
    float* A       = (float*)(ws + A_OFF);
    float* sumexp  = (float*)(ws + SUM_OFF);
    float* partial = (float*)(ws + PART_OFF);

    // DIAGNOSTIC: k_emit is pure/idempotent — launch 3x.
    // T_emit+gap = (dur - 125.2)/2, assumption-free.
    k_emit<<<NBLK, 256, 0, stream>>>(ThetaB, E, btn8, partial);
    k_emit<<<NBLK, 256, 0, stream>>>(ThetaB, E, btn8, partial);
    k_emit<<<NBLK, 256, 0, stream>>>(ThetaB, E, btn8, partial);
    k_sumA<<<KT, 256, 0, stream>>>(partial, WA, sumexp, A);
    k_scan3<<<8192 / 16, 128, 0, stream>>>(words, btn8, A, sumexp, out);
}

// Round 18
// 134.327 us; speedup vs baseline: 1.3299x; 1.2667x over previous
//
#include <hip/hip_runtime.h>
#include <hip/hip_bf16.h>
#include <math.h>

// HMM forward (logZ), K=64 tags, V=50000, D=128, BATCH=8192, L=126.
// r23: warm v2 — HW XCC_ID + per-XCD ticket. Closed ledger (r21+r22):
// r18's 125.2 = fill 44.5 + emit 19.5 + sumA 4 + scan 57(COLD) + ~0 gaps;
// warm repeat scan = 26.7 (r21). The 30us cold delta = one-time service
// of the 3.2MB btn8 table to reader XCDs via RANDOM 64B L3 fills (~2TB/s);
// warm gathers hit local L2 (34TB/s). r20's slice-warm (bid>>3 under
// assumed bid%8 round-robin) was null -> hypothesis: block->XCD mapping is
// CHUNKED (2 blocks/CU: blocks 0-63 -> XCD0, ...) so each XCD warmed only
// 8/64 slices. Fix: read the REAL XCD id via s_getreg(HW_REG_XCC_ID)
// [learn_hip m09] + per-XCD atomicAdd ticket; slice = ticket & 63 -> the
// ~64 blocks resident on each XCD cover all 64 slices regardless of
// mapping, streaming the table SEQUENTIALLY (fast L3) into local L2.
// Ticket counters zeroed by k_sumA (always precedes scan; no extra node).
// Chains/emit/sumA byte-identical r18 -> absmax 8.0.
// Prediction: scan 57 -> ~27 (warm ~4 + L2-chains ~23); dur ~95-102.
// If ~125 again: L2-warm family falsified; pivot to emit store coalescing.
//
// fp8 row layout: tag k = 32*h + 8*qA + j  ->  byte 16*qA + 8*h + j.
//
// ws layout:
//   [0, 3,200,000)        btn8[v][64]   fp8e4m3  raw exp(logit), permuted order
//   [3,200,000, +16384)   A[i][j]       f32      softmax(WA, col BOS=-inf)+EPS
//   [3,216,384, +256)     sumexp[k]     f32
//   [3,216,640, +200704)  partial[k][784] f32    per-block column sums
//   [3,417,344, +32)      xcnt[8]       u32      per-XCD warm tickets

#define KT 64
#define VV 50000
#define DD 128
#define BOS_T 62
#define EOS_T 63
#define LLEN 126
#define EPSF 1e-45f
#define SCALE_F 65536.0f
#define LOG_TOTAL_SCALE (2016.0f * 0.6931471805599453f)
#define NBLK 782          // k_emit grid
#define PBLK 784          // padded partial row
#define PFD 9             // prefetch depth
#define HSTEPS 63         // steps per direction (126/2)
#define HROUNDS (HSTEPS / PFD)   // 7
#define WARM_U4 3125      // 50,000 B per slice / 16

#define BTN_OFF   0
#define A_OFF     3200000
#define SUM_OFF   3216384
#define PART_OFF  3216640
#define XCNT_OFF  3417344

typedef short short8 __attribute__((ext_vector_type(8)));
typedef float f32x4  __attribute__((ext_vector_type(4)));
typedef float f32x2  __attribute__((ext_vector_type(2)));

union U8 { short8 v; unsigned u[4]; short s[8]; };

static __device__ inline unsigned short f2bf_u(float x) {
    __hip_bfloat16 h = __float2bfloat16(x);
    return *reinterpret_cast<unsigned short*>(&h);
}
static __device__ inline short f2bf(float x) { return (short)f2bf_u(x); }
static __device__ inline float bf2f(short s) {
    union { unsigned u; float f; } c;
    c.u = ((unsigned)(unsigned short)s) << 16;
    return c.f;
}

#if __has_builtin(__builtin_amdgcn_cvt_pk_bf16_f32)
typedef __bf16 bf16x2 __attribute__((ext_vector_type(2)));
static __device__ inline unsigned pk2(float a, float b) {
    bf16x2 r = __builtin_amdgcn_cvt_pk_bf16_f32(a, b);
    return *reinterpret_cast<unsigned*>(&r);
}
#else
static __device__ inline unsigned pk2(float a, float b) {
    union { float f; unsigned u; } ua, ub;
    ua.f = a; ub.f = b;
    return ((ua.u + 0x8000u) >> 16) | ((ub.u + 0x8000u) & 0xFFFF0000u);
}
#endif

// ---- fp8 e4m3fn pack/unpack (values here are positive normals in [0.7,1.5])
#if __has_builtin(__builtin_amdgcn_cvt_pk_fp8_f32)
static __device__ inline unsigned pk4f8(float a, float b, float c, float d) {
    int v = __builtin_amdgcn_cvt_pk_fp8_f32(a, b, 0, false);
    v = __builtin_amdgcn_cvt_pk_fp8_f32(c, d, v, true);
    return (unsigned)v;
}
#else
static __device__ inline unsigned enc1f8(float x) {
    union { float f; unsigned u; } c; c.f = x;
    unsigned u = c.u & 0x7FFFFFFFu;
    unsigned r = u + 0x7FFFFu + ((u >> 20) & 1u);   // RNE to 3 mantissa bits
    return ((r >> 20) - (120u << 3)) & 0x7Fu;       // rebias 127->7
}
static __device__ inline unsigned pk4f8(float a, float b, float c, float d) {
    return enc1f8(a) | (enc1f8(b) << 8) | (enc1f8(c) << 16) | (enc1f8(d) << 24);
}
#endif

#if __has_builtin(__builtin_amdgcn_cvt_pk_f32_fp8)
static __device__ inline f32x2 dec2lo(unsigned w) { return __builtin_amdgcn_cvt_pk_f32_fp8((int)w, false); }
static __device__ inline f32x2 dec2hi(unsigned w) { return __builtin_amdgcn_cvt_pk_f32_fp8((int)w, true); }
#else
static __device__ inline float dec1f8(unsigned b) {
    union { unsigned u; float f; } c;
    c.u = ((b & 0x80u) << 24) | (((b & 0x7Fu) << 20) + (120u << 23));
    return c.f;
}
static __device__ inline f32x2 dec2lo(unsigned w) { f32x2 r; r.x = dec1f8(w & 0xFF); r.y = dec1f8((w >> 8) & 0xFF); return r; }
static __device__ inline f32x2 dec2hi(unsigned w) { f32x2 r; r.x = dec1f8((w >> 16) & 0xFF); r.y = dec1f8(w >> 24); return r; }
#endif

// ---------------------------------------------------------------- btn8[v][pos(k)] = fp8(exp(ThetaB[k].E[v]))  (MFMA GEMM)
__global__ __launch_bounds__(256) void k_emit(const float* __restrict__ ThetaB,
                                              const float* __restrict__ E,
                                              unsigned char* __restrict__ btn8,
                                              float* __restrict__ partial) {
    __shared__ float red[4][KT];
    int t    = threadIdx.x;
    int lane = t & 63;
    int w    = t >> 6;
    int n    = lane & 15;
    int q    = lane >> 4;
    int v0   = (blockIdx.x * 4 + w) * 16;

    int rowE = v0 + n;
    bool valid = rowE < VV;
    rowE = valid ? rowE : VV - 1;
    float4 ex[4][2];
#pragma unroll
    for (int kt = 0; kt < 4; ++kt) {
        const float* p = E + (size_t)rowE * DD + kt * 32 + q * 8;
        ex[kt][0] = *(const float4*)p;
        ex[kt][1] = *(const float4*)(p + 4);
    }

    short8 Th[4][4];
#pragma unroll
    for (int kt = 0; kt < 4; ++kt)
#pragma unroll
        for (int mt = 0; mt < 4; ++mt) {
            const float* p = ThetaB + (mt * 16 + n) * DD + kt * 32 + q * 8;
            float4 x = *(const float4*)p;
            float4 y = *(const float4*)(p + 4);
            U8 f;
            f.u[0] = pk2(x.x, x.y); f.u[1] = pk2(x.z, x.w);
            f.u[2] = pk2(y.x, y.y); f.u[3] = pk2(y.z, y.w);
            Th[kt][mt] = f.v;
        }

    short8 Ef[4];
#pragma unroll
    for (int kt = 0; kt < 4; ++kt) {
        U8 f;
        f.u[0] = pk2(ex[kt][0].x, ex[kt][0].y); f.u[1] = pk2(ex[kt][0].z, ex[kt][0].w);
        f.u[2] = pk2(ex[kt][1].x, ex[kt][1].y); f.u[3] = pk2(ex[kt][1].z, ex[kt][1].w);
        Ef[kt] = f.v;
    }

#pragma unroll
    for (int mt = 0; mt < 4; ++mt) {
        f32x4 C = {0.f, 0.f, 0.f, 0.f};
#pragma unroll
        for (int kt = 0; kt < 4; ++kt)
            C = __builtin_amdgcn_mfma_f32_16x16x32_bf16(Th[kt][mt], Ef[kt], C, 0, 0, 0);
        float e[4];
#pragma unroll
        for (int r = 0; r < 4; ++r) e[r] = __expf(C[r]);
        if (valid) {
            // tag tt = mt*16 + q*4 + r -> byte 16*qA + 8*h + j
            int pos = 16 * ((2 * mt + (q >> 1)) & 3) + 8 * (mt >> 1) + (q & 1) * 4;
            *(unsigned*)(btn8 + (size_t)rowE * KT + pos) = pk4f8(e[0], e[1], e[2], e[3]);
        }
#pragma unroll
        for (int r = 0; r < 4; ++r) {
            float s = valid ? e[r] : 0.0f;
            s += __shfl_xor(s, 1, 64);
            s += __shfl_xor(s, 2, 64);
            s += __shfl_xor(s, 4, 64);
            s += __shfl_xor(s, 8, 64);
            if (n == 0) red[w][mt * 16 + q * 4 + r] = s;
        }
    }
    __syncthreads();
    if (w == 0) {
        float s = red[0][lane] + red[1][lane] + red[2][lane] + red[3][lane];
        partial[lane * PBLK + blockIdx.x] = s;
    }
}

// ---------------------------------------------------------------- sumexp[k] = sum partial[k][:]; A row k = softmax(WA row k)
// Also zeroes the 8 per-XCD warm-ticket counters (runs before k_scan3).
__global__ __launch_bounds__(256) void k_sumA(const float* __restrict__ partial,
                                              const float* __restrict__ WA,
                                              float* __restrict__ sumexp,
                                              float* __restrict__ A,
                                              unsigned* __restrict__ xcnt) {
    __shared__ float r[4];
    int k = blockIdx.x;
    int t = threadIdx.x;
    if (k == 0 && t < 8) xcnt[t] = 0u;
    float s = 0.0f;
    for (int i = t; i < NBLK; i += 256) s += partial[k * PBLK + i];
#pragma unroll
    for (int off = 32; off > 0; off >>= 1) s += __shfl_xor(s, off, 64);
    if ((t & 63) == 0) r[t >> 6] = s;
    __syncthreads();
    if (t == 0) sumexp[k] = r[0] + r[1] + r[2] + r[3];
    if (t < 64) {
        float wv = WA[k * KT + t];
        float e = (t == BOS_T) ? 0.0f : __expf(wv);
        float se = e;
#pragma unroll
        for (int off = 32; off > 0; off >>= 1) se += __shfl_xor(se, off, 64);
        A[k * KT + t] = e / se + EPSF;
    }
}

// ---------------------------------------------------------------- split scan
// 512 blocks x 128 threads (2 waves), 16 sentences per block.
// Prologue: warm v2 — real XCD id (s_getreg HW_REG_XCC_ID) + per-XCD
// atomic ticket; slice = ticket&63 -> blocks resident on each XCD cover
// all 64 slices (whole 3.2MB table -> local L2) regardless of mapping.
// wave0: alpha_63 forward; wave1: beta_63 backward; meet-in-middle dot.
__global__ __launch_bounds__(128) void k_scan3(const int* __restrict__ words,
                                               const unsigned char* __restrict__ btn8,
                                               const float* __restrict__ A,
                                               const float* __restrict__ sumexp,
                                               unsigned* __restrict__ xcnt,
                                               float* __restrict__ out) {
    __shared__ int shw[16 * LLEN];    // 8064 B
    __shared__ float scl[KT];         // 256 B
    __shared__ float ldx[KT][16];     // 4096 B  alpha_63 (tag, sentence)
    __shared__ float ldy[KT][16];     // 4096 B  beta_63
    __shared__ int slice_s;
    int t    = threadIdx.x;
    int lane = t & 63;
    int w    = t >> 6;                // 0 = forward, 1 = backward
    int n    = lane & 15;
    int qA   = lane >> 4;
    int b0   = blockIdx.x * 16;

    // warm ticket: real XCD id + per-XCD atomic counter
    if (t == 0) {
        unsigned xcc;
        asm volatile("s_getreg_b32 %0, hwreg(HW_REG_XCC_ID)" : "=s"(xcc));
        unsigned ticket = atomicAdd(xcnt + (xcc & 7u), 1u);
        slice_s = (int)(ticket & 63u);
    }

    // stage word indices (both waves cooperate)
    {
        const uint4* src = (const uint4*)(words + (size_t)b0 * LLEN);
        uint4* dst = (uint4*)shw;
        for (int idx = t; idx < (16 * LLEN) / 4; idx += 128)
            dst[idx] = src[idx];
    }
    // contracted-tag scale table for the backward A-operand
    if (t < KT)
        scl[t] = (t == BOS_T || t == EOS_T) ? 0.0f : (SCALE_F / sumexp[t]);
    __syncthreads();

    // ---- L2 warm: stream this block's assigned 50KB slice (sequential L3
    // -> local L2 as clean lines); keep loads alive against DCE.
    {
        const uint4* p = (const uint4*)btn8 + (size_t)slice_s * WARM_U4;
        unsigned acc = 0;
        for (int i = t; i < WARM_U4; i += 128) {
            uint4 v = p[i];
            acc ^= v.x ^ v.y ^ v.z ^ v.w;
        }
        asm volatile("" :: "v"(acc));
    }

    const int wrow = n * LLEN;

    if (w == 0) {
        // ================= forward: words 0..62 from one-hot BOS =================
        short8 Af[2][4];
#pragma unroll
        for (int mt = 0; mt < 4; ++mt) {
            int tagn = 32 * (mt >> 1) + 8 * (n >> 2) + 4 * (mt & 1) + (n & 3);
            float s = sumexp[tagn];
            float rsn = (tagn == BOS_T || tagn == EOS_T) ? 0.0f : (SCALE_F / s);
#pragma unroll
            for (int kt = 0; kt < 2; ++kt) {
                U8 f;
#pragma unroll
                for (int j = 0; j < 8; ++j)
                    f.s[j] = f2bf(A[(kt * 32 + qA * 8 + j) * KT + tagn] * rsn);
                Af[kt][mt] = f.v;
            }
        }
        short8 B0, B1;
        {
            U8 z; z.u[0] = z.u[1] = z.u[2] = z.u[3] = 0;
            B0 = z.v;
            U8 o; o.u[0] = o.u[1] = o.u[2] = o.u[3] = 0;
            if (qA == 3) o.s[6] = (short)0x3F80;   // bf16(1.0) at tag 62 = BOS
            B1 = o.v;
        }

        uint4 pf[PFD];
        int   wdn[PFD];
#pragma unroll
        for (int j = 0; j < PFD; ++j) {
            int wd = shw[wrow + j];
            pf[j] = *(const uint4*)(btn8 + (size_t)wd * KT + qA * 16);
        }
#pragma unroll
        for (int j = 0; j < PFD; ++j)
            wdn[j] = shw[wrow + PFD + j];

        for (int r = 0; r < HROUNDS; ++r) {
#pragma unroll
            for (int j = 0; j < PFD; ++j) {
                uint4 rc = pf[j];
                pf[j] = *(const uint4*)(btn8 + (size_t)wdn[j] * KT + qA * 16);
                int s18 = r * PFD + j + 2 * PFD;
                s18 = s18 < HSTEPS ? s18 : HSTEPS - 1;
                wdn[j] = shw[wrow + s18];

                f32x2 d0 = dec2lo(rc.x), d1 = dec2hi(rc.x);
                f32x2 d2 = dec2lo(rc.y), d3 = dec2hi(rc.y);
                f32x2 d4 = dec2lo(rc.z), d5 = dec2hi(rc.z);
                f32x2 d6 = dec2lo(rc.w), d7 = dec2hi(rc.w);

                f32x4 C[4];
#pragma unroll
                for (int mt = 0; mt < 4; ++mt) {
                    f32x4 acc = {0.f, 0.f, 0.f, 0.f};
                    acc = __builtin_amdgcn_mfma_f32_16x16x32_bf16(Af[0][mt], B0, acc, 0, 0, 0);
                    acc = __builtin_amdgcn_mfma_f32_16x16x32_bf16(Af[1][mt], B1, acc, 0, 0, 0);
                    C[mt] = acc;
                }
                U8 f0, f1;
                f0.u[0] = pk2(C[0][0] * d0.x, C[0][1] * d0.y);
                f0.u[1] = pk2(C[0][2] * d1.x, C[0][3] * d1.y);
                f0.u[2] = pk2(C[1][0] * d2.x, C[1][1] * d2.y);
                f0.u[3] = pk2(C[1][2] * d3.x, C[1][3] * d3.y);
                f1.u[0] = pk2(C[2][0] * d4.x, C[2][1] * d4.y);
                f1.u[1] = pk2(C[2][2] * d5.x, C[2][3] * d5.y);
                f1.u[2] = pk2(C[3][0] * d6.x, C[3][1] * d6.y);
                f1.u[3] = pk2(C[3][2] * d7.x, C[3][3] * d7.y);
                B0 = f0.v; B1 = f1.v;
            }
        }
        // x63 -> LDS: B-slot tag = kt*32 + qA*8 + j
        U8 bx0, bx1; bx0.v = B0; bx1.v = B1;
#pragma unroll
        for (int j = 0; j < 8; ++j) {
            ldx[qA * 8 + j][n]      = bf2f(bx0.s[j]);
            ldx[32 + qA * 8 + j][n] = bf2f(bx1.s[j]);
        }
    } else {
        // ================= backward: words 125..63 from y_T = A[:,EOS] ==========
        short8 Af[2][4];
#pragma unroll
        for (int mt = 0; mt < 4; ++mt) {
            int tagn = 32 * (mt >> 1) + 8 * (n >> 2) + 4 * (mt & 1) + (n & 3);
#pragma unroll
            for (int kt = 0; kt < 2; ++kt) {
                U8 f;
#pragma unroll
                for (int j = 0; j < 8; ++j) {
                    int kc = kt * 32 + qA * 8 + j;
                    f.s[j] = f2bf(A[tagn * KT + kc] * scl[kc]);
                }
                Af[kt][mt] = f.v;
            }
        }
        // y_T in C-layout: C[mt][r] at (n, qA) = A[tag(mt,qA,r), EOS]
        f32x4 C[4];
#pragma unroll
        for (int mt = 0; mt < 4; ++mt)
#pragma unroll
            for (int r = 0; r < 4; ++r) {
                int tg = 32 * (mt >> 1) + 8 * qA + 4 * (mt & 1) + r;
                C[mt][r] = A[tg * KT + EOS_T];
            }

        uint4 pf[PFD];
        int   wdn[PFD];
#pragma unroll
        for (int j = 0; j < PFD; ++j) {
            int wd = shw[wrow + (LLEN - 1 - j)];
            pf[j] = *(const uint4*)(btn8 + (size_t)wd * KT + qA * 16);
        }
#pragma unroll
        for (int j = 0; j < PFD; ++j)
            wdn[j] = shw[wrow + (LLEN - 1 - (PFD + j))];

        for (int r = 0; r < HROUNDS; ++r) {
#pragma unroll
            for (int j = 0; j < PFD; ++j) {
                uint4 rc = pf[j];
                pf[j] = *(const uint4*)(btn8 + (size_t)wdn[j] * KT + qA * 16);
                int itn = r * PFD + j + 2 * PFD;
                itn = itn < HSTEPS ? itn : HSTEPS - 1;
                wdn[j] = shw[wrow + (LLEN - 1 - itn)];

                f32x2 d0 = dec2lo(rc.x), d1 = dec2hi(rc.x);
                f32x2 d2 = dec2lo(rc.y), d3 = dec2hi(rc.y);
                f32x2 d4 = dec2lo(rc.z), d5 = dec2hi(rc.z);
                f32x2 d6 = dec2lo(rc.w), d7 = dec2hi(rc.w);

                // B = pk2(C .* e)  (elementwise BEFORE matvec in bwd)
                U8 f0, f1;
                f0.u[0] = pk2(C[0][0] * d0.x, C[0][1] * d0.y);
                f0.u[1] = pk2(C[0][2] * d1.x, C[0][3] * d1.y);
                f0.u[2] = pk2(C[1][0] * d2.x, C[1][1] * d2.y);
                f0.u[3] = pk2(C[1][2] * d3.x, C[1][3] * d3.y);
                f1.u[0] = pk2(C[2][0] * d4.x, C[2][1] * d4.y);
                f1.u[1] = pk2(C[2][2] * d5.x, C[2][3] * d5.y);
                f1.u[2] = pk2(C[3][0] * d6.x, C[3][1] * d6.y);
                f1.u[3] = pk2(C[3][2] * d7.x, C[3][3] * d7.y);
                short8 B0 = f0.v, B1 = f1.v;

#pragma unroll
                for (int mt = 0; mt < 4; ++mt) {
                    f32x4 acc = {0.f, 0.f, 0.f, 0.f};
                    acc = __builtin_amdgcn_mfma_f32_16x16x32_bf16(Af[0][mt], B0, acc, 0, 0, 0);
                    acc = __builtin_amdgcn_mfma_f32_16x16x32_bf16(Af[1][mt], B1, acc, 0, 0, 0);
                    C[mt] = acc;
                }
            }
        }
        // y63 -> LDS: C-position tag = 32*(mt>>1) + 8*qA + 4*(mt&1) + r
#pragma unroll
        for (int mt = 0; mt < 4; ++mt)
#pragma unroll
            for (int r = 0; r < 4; ++r) {
                int tg = 32 * (mt >> 1) + 8 * qA + 4 * (mt & 1) + r;
                ldy[tg][n] = C[mt][r];
            }
    }
    __syncthreads();

    // combine: logZ[n] = log(sum_tag x*y) - LOG_TOTAL_SCALE  (wave 0)
    if (w == 0) {
        float s = 0.0f;
#pragma unroll
        for (int kk = 0; kk < 16; ++kk) {
            int tg = qA * 16 + kk;
            s += ldx[tg][n] * ldy[tg][n];
        }
        s += __shfl_xor(s, 16, 64);
        s += __shfl_xor(s, 32, 64);
        if (qA == 0)
            out[b0 + n] = logf(s) - LOG_TOTAL_SCALE;
    }
}

extern "C" void kernel_launch(void* const* d_in, const int* in_sizes, int n_in,
                              void* d_out, int out_size, void* d_ws, size_t ws_size,
                              hipStream_t stream) {
    const int*   words  = (const int*)d_in[0];     // [8192,126]
    const float* ThetaB = (const float*)d_in[1];   // [64,128]
    const float* WA     = (const float*)d_in[2];   // [64,64]
    const float* E      = (const float*)d_in[3];   // [50000,128]
    float* out = (float*)d_out;                    // [8192]

    char* ws = (char*)d_ws;
    unsigned char* btn8 = (unsigned char*)(ws + BTN_OFF);
    float* A        = (float*)(ws + A_OFF);
    float* sumexp   = (float*)(ws + SUM_OFF);
    float* partial  = (float*)(ws + PART_OFF);
    unsigned* xcnt  = (unsigned*)(ws + XCNT_OFF);

    k_emit<<<NBLK, 256, 0, stream>>>(ThetaB, E, btn8, partial);
    k_sumA<<<KT, 256, 0, stream>>>(partial, WA, sumexp, A, xcnt);
    k_scan3<<<8192 / 16, 128, 0, stream>>>(words, btn8, A, sumexp, xcnt, out);
}

// Round 19
// 125.896 us; speedup vs baseline: 1.4190x; 1.0670x over previous
//
#include <hip/hip_runtime.h>
#include <hip/hip_bf16.h>
#include <math.h>

// HMM forward (logZ), K=64 tags, V=50000, D=128, BATCH=8192, L=126.
// r24: revert warm (r23: +9us, third null on the L2-warm family — dead);
// coalesce k_emit's btn8 stores. Closed ledger for r18's 125.2:
//   fill 44.5 (fixed) + emit 19.5 (r22) + sumA ~4 + scan ~38 (r23 direct:
//   47.6 incl. ~10 warm; r21 warm-rerun 22-24) + gaps ~19 (4-5 x ~5us).
// The scan's ~400-700cy/step stall (VALUBusy 19%, MfmaUtil 6%, HBM 4%,
// Occ 10%) survived 4 redesigns + 3 locality attacks -> parked.
// Emit is the unexploited measured line: 19.5 vs ~8 model. Its btn8
// stores are 256 scattered 4B stores/wave (r19: replicating them 8x cost
// +11us for 22MB -> the 4B-scatter path is expensive). Fix: per-wave LDS
// bounce tile [16][17 u32] (padded), then each lane stores one 16B chunk
// of a contiguous 1KB block (16 rows x 64B). Bitwise-identical btn8;
// partial/column sums untouched. Scan/sumA = verbatim r18 (best, 125.2).
// Prediction: emit 19.5 -> 11-13 => dur ~115-119; absmax 8.0.
//
// fp8 row layout: tag k = 32*h + 8*qA + j  ->  byte 16*qA + 8*h + j.
//
// ws layout (r12):
//   [0, 3,200,000)        btn8[v][64]   fp8e4m3  raw exp(logit), permuted order
//   [3,200,000, +16384)   A[i][j]       f32      softmax(WA, col BOS=-inf)+EPS
//   [3,216,384, +256)     sumexp[k]     f32
//   [3,216,640, +200704)  partial[k][784] f32    per-block column sums

#define KT 64
#define VV 50000
#define DD 128
#define BOS_T 62
#define EOS_T 63
#define LLEN 126
#define EPSF 1e-45f
#define SCALE_F 65536.0f
#define LOG_TOTAL_SCALE (2016.0f * 0.6931471805599453f)
#define NBLK 782          // k_emit grid
#define PBLK 784          // padded partial row
#define PFD 9             // prefetch depth
#define HSTEPS 63         // steps per direction (126/2)
#define HROUNDS (HSTEPS / PFD)   // 7

#define BTN_OFF   0
#define A_OFF     3200000
#define SUM_OFF   3216384
#define PART_OFF  3216640

typedef short short8 __attribute__((ext_vector_type(8)));
typedef float f32x4  __attribute__((ext_vector_type(4)));
typedef float f32x2  __attribute__((ext_vector_type(2)));

union U8 { short8 v; unsigned u[4]; short s[8]; };

static __device__ inline unsigned short f2bf_u(float x) {
    __hip_bfloat16 h = __float2bfloat16(x);
    return *reinterpret_cast<unsigned short*>(&h);
}
static __device__ inline short f2bf(float x) { return (short)f2bf_u(x); }
static __device__ inline float bf2f(short s) {
    union { unsigned u; float f; } c;
    c.u = ((unsigned)(unsigned short)s) << 16;
    return c.f;
}

#if __has_builtin(__builtin_amdgcn_cvt_pk_bf16_f32)
typedef __bf16 bf16x2 __attribute__((ext_vector_type(2)));
static __device__ inline unsigned pk2(float a, float b) {
    bf16x2 r = __builtin_amdgcn_cvt_pk_bf16_f32(a, b);
    return *reinterpret_cast<unsigned*>(&r);
}
#else
static __device__ inline unsigned pk2(float a, float b) {
    union { float f; unsigned u; } ua, ub;
    ua.f = a; ub.f = b;
    return ((ua.u + 0x8000u) >> 16) | ((ub.u + 0x8000u) & 0xFFFF0000u);
}
#endif

// ---- fp8 e4m3fn pack/unpack (values here are positive normals in [0.7,1.5])
#if __has_builtin(__builtin_amdgcn_cvt_pk_fp8_f32)
static __device__ inline unsigned pk4f8(float a, float b, float c, float d) {
    int v = __builtin_amdgcn_cvt_pk_fp8_f32(a, b, 0, false);
    v = __builtin_amdgcn_cvt_pk_fp8_f32(c, d, v, true);
    return (unsigned)v;
}
#else
static __device__ inline unsigned enc1f8(float x) {
    union { float f; unsigned u; } c; c.f = x;
    unsigned u = c.u & 0x7FFFFFFFu;
    unsigned r = u + 0x7FFFFu + ((u >> 20) & 1u);   // RNE to 3 mantissa bits
    return ((r >> 20) - (120u << 3)) & 0x7Fu;       // rebias 127->7
}
static __device__ inline unsigned pk4f8(float a, float b, float c, float d) {
    return enc1f8(a) | (enc1f8(b) << 8) | (enc1f8(c) << 16) | (enc1f8(d) << 24);
}
#endif

#if __has_builtin(__builtin_amdgcn_cvt_pk_f32_fp8)
static __device__ inline f32x2 dec2lo(unsigned w) { return __builtin_amdgcn_cvt_pk_f32_fp8((int)w, false); }
static __device__ inline f32x2 dec2hi(unsigned w) { return __builtin_amdgcn_cvt_pk_f32_fp8((int)w, true); }
#else
static __device__ inline float dec1f8(unsigned b) {
    union { unsigned u; float f; } c;
    c.u = ((b & 0x80u) << 24) | (((b & 0x7Fu) << 20) + (120u << 23));
    return c.f;
}
static __device__ inline f32x2 dec2lo(unsigned w) { f32x2 r; r.x = dec1f8(w & 0xFF); r.y = dec1f8((w >> 8) & 0xFF); return r; }
static __device__ inline f32x2 dec2hi(unsigned w) { f32x2 r; r.x = dec1f8((w >> 16) & 0xFF); r.y = dec1f8(w >> 24); return r; }
#endif

// ---------------------------------------------------------------- btn8[v][pos(k)] = fp8(exp(ThetaB[k].E[v]))  (MFMA GEMM)
// Stores bounced through a per-wave LDS tile -> one contiguous 1KB block
// (16 rows x 64B) written as 64 lanes x 16B. Bitwise-identical bytes.
__global__ __launch_bounds__(256) void k_emit(const float* __restrict__ ThetaB,
                                              const float* __restrict__ E,
                                              unsigned char* __restrict__ btn8,
                                              float* __restrict__ partial) {
    __shared__ float red[4][KT];
    __shared__ unsigned st[4][16][17];   // [wave][row][16 u32 + pad]
    int t    = threadIdx.x;
    int lane = t & 63;
    int w    = t >> 6;
    int n    = lane & 15;
    int q    = lane >> 4;
    int v0   = (blockIdx.x * 4 + w) * 16;

    int rowE = v0 + n;
    bool valid = rowE < VV;
    rowE = valid ? rowE : VV - 1;
    float4 ex[4][2];
#pragma unroll
    for (int kt = 0; kt < 4; ++kt) {
        const float* p = E + (size_t)rowE * DD + kt * 32 + q * 8;
        ex[kt][0] = *(const float4*)p;
        ex[kt][1] = *(const float4*)(p + 4);
    }

    short8 Th[4][4];
#pragma unroll
    for (int kt = 0; kt < 4; ++kt)
#pragma unroll
        for (int mt = 0; mt < 4; ++mt) {
            const float* p = ThetaB + (mt * 16 + n) * DD + kt * 32 + q * 8;
            float4 x = *(const float4*)p;
            float4 y = *(const float4*)(p + 4);
            U8 f;
            f.u[0] = pk2(x.x, x.y); f.u[1] = pk2(x.z, x.w);
            f.u[2] = pk2(y.x, y.y); f.u[3] = pk2(y.z, y.w);
            Th[kt][mt] = f.v;
        }

    short8 Ef[4];
#pragma unroll
    for (int kt = 0; kt < 4; ++kt) {
        U8 f;
        f.u[0] = pk2(ex[kt][0].x, ex[kt][0].y); f.u[1] = pk2(ex[kt][0].z, ex[kt][0].w);
        f.u[2] = pk2(ex[kt][1].x, ex[kt][1].y); f.u[3] = pk2(ex[kt][1].z, ex[kt][1].w);
        Ef[kt] = f.v;
    }

#pragma unroll
    for (int mt = 0; mt < 4; ++mt) {
        f32x4 C = {0.f, 0.f, 0.f, 0.f};
#pragma unroll
        for (int kt = 0; kt < 4; ++kt)
            C = __builtin_amdgcn_mfma_f32_16x16x32_bf16(Th[kt][mt], Ef[kt], C, 0, 0, 0);
        float e[4];
#pragma unroll
        for (int r = 0; r < 4; ++r) e[r] = __expf(C[r]);
        // permuted u32 index of tag tt = mt*16 + q*4 + r within row n:
        // byte pos = 16*((2mt+(q>>1))&3) + 8*(mt>>1) + (q&1)*4  ->  /4
        {
            int idx = 4 * ((2 * mt + (q >> 1)) & 3) + 2 * (mt >> 1) + (q & 1);
            st[w][n][idx] = pk4f8(e[0], e[1], e[2], e[3]);
        }
        // column sums: reduce over the 16 v-lanes (lane bits 0-3)
#pragma unroll
        for (int r = 0; r < 4; ++r) {
            float s = valid ? e[r] : 0.0f;
            s += __shfl_xor(s, 1, 64);
            s += __shfl_xor(s, 2, 64);
            s += __shfl_xor(s, 4, 64);
            s += __shfl_xor(s, 8, 64);
            if (n == 0) red[w][mt * 16 + q * 4 + r] = s;
        }
    }
    // copy-out: lane l -> row v0+(l>>2), u32s (l&3)*4..+3  (contiguous 1KB/wave)
    {
        int row = lane >> 2;
        int c0  = (lane & 3) * 4;
        if (v0 + row < VV) {
            uint4 val;
            val.x = st[w][row][c0 + 0];
            val.y = st[w][row][c0 + 1];
            val.z = st[w][row][c0 + 2];
            val.w = st[w][row][c0 + 3];
            *(uint4*)(btn8 + (size_t)(v0 + row) * KT + c0 * 4) = val;
        }
    }
    __syncthreads();
    if (w == 0) {
        float s = red[0][lane] + red[1][lane] + red[2][lane] + red[3][lane];
        partial[lane * PBLK + blockIdx.x] = s;
    }
}

// ---------------------------------------------------------------- sumexp[k] = sum partial[k][:]; A row k = softmax(WA row k)
__global__ __launch_bounds__(256) void k_sumA(const float* __restrict__ partial,
                                              const float* __restrict__ WA,
                                              float* __restrict__ sumexp,
                                              float* __restrict__ A) {
    __shared__ float r[4];
    int k = blockIdx.x;
    int t = threadIdx.x;
    float s = 0.0f;
    for (int i = t; i < NBLK; i += 256) s += partial[k * PBLK + i];
#pragma unroll
    for (int off = 32; off > 0; off >>= 1) s += __shfl_xor(s, off, 64);
    if ((t & 63) == 0) r[t >> 6] = s;
    __syncthreads();
    if (t == 0) sumexp[k] = r[0] + r[1] + r[2] + r[3];
    if (t < 64) {
        float wv = WA[k * KT + t];
        float e = (t == BOS_T) ? 0.0f : __expf(wv);
        float se = e;
#pragma unroll
        for (int off = 32; off > 0; off >>= 1) se += __shfl_xor(se, off, 64);
        A[k * KT + t] = e / se + EPSF;
    }
}

// ---------------------------------------------------------------- split scan
// 512 blocks x 128 threads (2 waves), 16 sentences per block.
// wave0: alpha_63 forward (words 0..62). wave1: beta_63 backward
// (words 125..63), y <- A''(e .* y) from A[:,EOS].
// Combine: logZ = log(sum x*y) - LOG_TOTAL_SCALE.
__global__ __launch_bounds__(128) void k_scan3(const int* __restrict__ words,
                                               const unsigned char* __restrict__ btn8,
                                               const float* __restrict__ A,
                                               const float* __restrict__ sumexp,
                                               float* __restrict__ out) {
    __shared__ int shw[16 * LLEN];    // 8064 B
    __shared__ float scl[KT];         // 256 B
    __shared__ float ldx[KT][16];     // 4096 B  alpha_63 (tag, sentence)
    __shared__ float ldy[KT][16];     // 4096 B  beta_63
    int t    = threadIdx.x;
    int lane = t & 63;
    int w    = t >> 6;                // 0 = forward, 1 = backward
    int n    = lane & 15;
    int qA   = lane >> 4;
    int b0   = blockIdx.x * 16;

    // stage word indices (both waves cooperate)
    {
        const uint4* src = (const uint4*)(words + (size_t)b0 * LLEN);
        uint4* dst = (uint4*)shw;
        for (int idx = t; idx < (16 * LLEN) / 4; idx += 128)
            dst[idx] = src[idx];
    }
    // contracted-tag scale table for the backward A-operand
    if (t < KT)
        scl[t] = (t == BOS_T || t == EOS_T) ? 0.0f : (SCALE_F / sumexp[t]);
    __syncthreads();

    const int wrow = n * LLEN;

    if (w == 0) {
        // ================= forward: words 0..62 from one-hot BOS =================
        short8 Af[2][4];
#pragma unroll
        for (int mt = 0; mt < 4; ++mt) {
            int tagn = 32 * (mt >> 1) + 8 * (n >> 2) + 4 * (mt & 1) + (n & 3);
            float s = sumexp[tagn];
            float rsn = (tagn == BOS_T || tagn == EOS_T) ? 0.0f : (SCALE_F / s);
#pragma unroll
            for (int kt = 0; kt < 2; ++kt) {
                U8 f;
#pragma unroll
                for (int j = 0; j < 8; ++j)
                    f.s[j] = f2bf(A[(kt * 32 + qA * 8 + j) * KT + tagn] * rsn);
                Af[kt][mt] = f.v;
            }
        }
        short8 B0, B1;
        {
            U8 z; z.u[0] = z.u[1] = z.u[2] = z.u[3] = 0;
            B0 = z.v;
            U8 o; o.u[0] = o.u[1] = o.u[2] = o.u[3] = 0;
            if (qA == 3) o.s[6] = (short)0x3F80;   // bf16(1.0) at tag 62 = BOS
            B1 = o.v;
        }

        uint4 pf[PFD];
        int   wdn[PFD];
#pragma unroll
        for (int j = 0; j < PFD; ++j) {
            int wd = shw[wrow + j];
            pf[j] = *(const uint4*)(btn8 + (size_t)wd * KT + qA * 16);
        }
#pragma unroll
        for (int j = 0; j < PFD; ++j)
            wdn[j] = shw[wrow + PFD + j];

        for (int r = 0; r < HROUNDS; ++r) {
#pragma unroll
            for (int j = 0; j < PFD; ++j) {
                uint4 rc = pf[j];
                pf[j] = *(const uint4*)(btn8 + (size_t)wdn[j] * KT + qA * 16);
                int s18 = r * PFD + j + 2 * PFD;
                s18 = s18 < HSTEPS ? s18 : HSTEPS - 1;
                wdn[j] = shw[wrow + s18];

                f32x2 d0 = dec2lo(rc.x), d1 = dec2hi(rc.x);
                f32x2 d2 = dec2lo(rc.y), d3 = dec2hi(rc.y);
                f32x2 d4 = dec2lo(rc.z), d5 = dec2hi(rc.z);
                f32x2 d6 = dec2lo(rc.w), d7 = dec2hi(rc.w);

                f32x4 C[4];
#pragma unroll
                for (int mt = 0; mt < 4; ++mt) {
                    f32x4 acc = {0.f, 0.f, 0.f, 0.f};
                    acc = __builtin_amdgcn_mfma_f32_16x16x32_bf16(Af[0][mt], B0, acc, 0, 0, 0);
                    acc = __builtin_amdgcn_mfma_f32_16x16x32_bf16(Af[1][mt], B1, acc, 0, 0, 0);
                    C[mt] = acc;
                }
                U8 f0, f1;
                f0.u[0] = pk2(C[0][0] * d0.x, C[0][1] * d0.y);
                f0.u[1] = pk2(C[0][2] * d1.x, C[0][3] * d1.y);
                f0.u[2] = pk2(C[1][0] * d2.x, C[1][1] * d2.y);
                f0.u[3] = pk2(C[1][2] * d3.x, C[1][3] * d3.y);
                f1.u[0] = pk2(C[2][0] * d4.x, C[2][1] * d4.y);
                f1.u[1] = pk2(C[2][2] * d5.x, C[2][3] * d5.y);
                f1.u[2] = pk2(C[3][0] * d6.x, C[3][1] * d6.y);
                f1.u[3] = pk2(C[3][2] * d7.x, C[3][3] * d7.y);
                B0 = f0.v; B1 = f1.v;
            }
        }
        // x63 -> LDS: B-slot tag = kt*32 + qA*8 + j
        U8 bx0, bx1; bx0.v = B0; bx1.v = B1;
#pragma unroll
        for (int j = 0; j < 8; ++j) {
            ldx[qA * 8 + j][n]      = bf2f(bx0.s[j]);
            ldx[32 + qA * 8 + j][n] = bf2f(bx1.s[j]);
        }
    } else {
        // ================= backward: words 125..63 from y_T = A[:,EOS] ==========
        short8 Af[2][4];
#pragma unroll
        for (int mt = 0; mt < 4; ++mt) {
            int tagn = 32 * (mt >> 1) + 8 * (n >> 2) + 4 * (mt & 1) + (n & 3);
#pragma unroll
            for (int kt = 0; kt < 2; ++kt) {
                U8 f;
#pragma unroll
                for (int j = 0; j < 8; ++j) {
                    int kc = kt * 32 + qA * 8 + j;
                    f.s[j] = f2bf(A[tagn * KT + kc] * scl[kc]);
                }
                Af[kt][mt] = f.v;
            }
        }
        // y_T in C-layout: C[mt][r] at (n, qA) = A[tag(mt,qA,r), EOS]
        f32x4 C[4];
#pragma unroll
        for (int mt = 0; mt < 4; ++mt)
#pragma unroll
            for (int r = 0; r < 4; ++r) {
                int tg = 32 * (mt >> 1) + 8 * qA + 4 * (mt & 1) + r;
                C[mt][r] = A[tg * KT + EOS_T];
            }

        uint4 pf[PFD];
        int   wdn[PFD];
#pragma unroll
        for (int j = 0; j < PFD; ++j) {
            int wd = shw[wrow + (LLEN - 1 - j)];
            pf[j] = *(const uint4*)(btn8 + (size_t)wd * KT + qA * 16);
        }
#pragma unroll
        for (int j = 0; j < PFD; ++j)
            wdn[j] = shw[wrow + (LLEN - 1 - (PFD + j))];

        for (int r = 0; r < HROUNDS; ++r) {
#pragma unroll
            for (int j = 0; j < PFD; ++j) {
                uint4 rc = pf[j];
                pf[j] = *(const uint4*)(btn8 + (size_t)wdn[j] * KT + qA * 16);
                int itn = r * PFD + j + 2 * PFD;
                itn = itn < HSTEPS ? itn : HSTEPS - 1;
                wdn[j] = shw[wrow + (LLEN - 1 - itn)];

                f32x2 d0 = dec2lo(rc.x), d1 = dec2hi(rc.x);
                f32x2 d2 = dec2lo(rc.y), d3 = dec2hi(rc.y);
                f32x2 d4 = dec2lo(rc.z), d5 = dec2hi(rc.z);
                f32x2 d6 = dec2lo(rc.w), d7 = dec2hi(rc.w);

                // B = pk2(C .* e)  (elementwise BEFORE matvec in bwd)
                U8 f0, f1;
                f0.u[0] = pk2(C[0][0] * d0.x, C[0][1] * d0.y);
                f0.u[1] = pk2(C[0][2] * d1.x, C[0][3] * d1.y);
                f0.u[2] = pk2(C[1][0] * d2.x, C[1][1] * d2.y);
                f0.u[3] = pk2(C[1][2] * d3.x, C[1][3] * d3.y);
                f1.u[0] = pk2(C[2][0] * d4.x, C[2][1] * d4.y);
                f1.u[1] = pk2(C[2][2] * d5.x, C[2][3] * d5.y);
                f1.u[2] = pk2(C[3][0] * d6.x, C[3][1] * d6.y);
                f1.u[3] = pk2(C[3][2] * d7.x, C[3][3] * d7.y);
                short8 B0 = f0.v, B1 = f1.v;

#pragma unroll
                for (int mt = 0; mt < 4; ++mt) {
                    f32x4 acc = {0.f, 0.f, 0.f, 0.f};
                    acc = __builtin_amdgcn_mfma_f32_16x16x32_bf16(Af[0][mt], B0, acc, 0, 0, 0);
                    acc = __builtin_amdgcn_mfma_f32_16x16x32_bf16(Af[1][mt], B1, acc, 0, 0, 0);
                    C[mt] = acc;
                }
            }
        }
        // y63 -> LDS: C-position tag = 32*(mt>>1) + 8*qA + 4*(mt&1) + r
#pragma unroll
        for (int mt = 0; mt < 4; ++mt)
#pragma unroll
            for (int r = 0; r < 4; ++r) {
                int tg = 32 * (mt >> 1) + 8 * qA + 4 * (mt & 1) + r;
                ldy[tg][n] = C[mt][r];
            }
    }
    __syncthreads();

    // combine: logZ[n] = log(sum_tag x*y) - LOG_TOTAL_SCALE  (wave 0)
    if (w == 0) {
        float s = 0.0f;
#pragma unroll
        for (int kk = 0; kk < 16; ++kk) {
            int tg = qA * 16 + kk;
            s += ldx[tg][n] * ldy[tg][n];
        }
        s += __shfl_xor(s, 16, 64);
        s += __shfl_xor(s, 32, 64);
        if (qA == 0)
            out[b0 + n] = logf(s) - LOG_TOTAL_SCALE;
    }
}

extern "C" void kernel_launch(void* const* d_in, const int* in_sizes, int n_in,
                              void* d_out, int out_size, void* d_ws, size_t ws_size,
                              hipStream_t stream) {
    const int*   words  = (const int*)d_in[0];     // [8192,126]
    const float* ThetaB = (const float*)d_in[1];   // [64,128]
    const float* WA     = (const float*)d_in[2];   // [64,64]
    const float* E      = (const float*)d_in[3];   // [50000,128]
    float* out = (float*)d_out;                    // [8192]

    char* ws = (char*)d_ws;
    unsigned char* btn8 = (unsigned char*)(ws + BTN_OFF);
    float* A       = (float*)(ws + A_OFF);
    float* sumexp  = (float*)(ws + SUM_OFF);
    float* partial = (float*)(ws + PART_OFF);

    k_emit<<<NBLK, 256, 0, stream>>>(ThetaB, E, btn8, partial);
    k_sumA<<<KT, 256, 0, stream>>>(partial, WA, sumexp, A);
    k_scan3<<<8192 / 16, 128, 0, stream>>>(words, btn8, A, sumexp, out);
}